// Round 1
// baseline (79.754 us; speedup 1.0000x reference)
//
#include <hip/hip_runtime.h>

// AdjacencyMatchingLoss: B=8, NL=NQ=128, E=50000
// loss = -(1/B) * sum_{i,j} M[i,j]*G[i,j] / max(sum_w,1e-8)
//   M[i,j] = scatter-add of edge weights at (pair0,pair1)
//   G[i,j] = sum_b (P[b] @ A) @ P[b]^T ,  A = (d_hw==1)

constexpr int NLQ = 128;   // NL == NQ
constexpr int PAD = 132;   // LDS row pad: stride 132 floats -> banks spread 4*(row)%32
constexpr int BATCH = 8;

__global__ __launch_bounds__(256) void edges_kernel(
    const int* __restrict__ pairs, const float* __restrict__ w,
    float* __restrict__ M, float* __restrict__ totw, int E)
{
    int idx = blockIdx.x * 256 + threadIdx.x;
    int stride = gridDim.x * 256;
    float wsum = 0.f;
    for (int e = idx; e < E; e += stride) {
        int i = pairs[2 * e];
        int j = pairs[2 * e + 1];
        float we = w[e];
        atomicAdd(&M[i * NLQ + j], we);
        wsum += we;
    }
    #pragma unroll
    for (int off = 32; off > 0; off >>= 1)
        wsum += __shfl_down(wsum, off, 64);
    if ((threadIdx.x & 63) == 0)
        atomicAdd(totw, wsum);
}

// One block per batch b. All operands staged in LDS, stored so that every
// inner-loop read is a row (contiguous / broadcast) access:
//   Pt[p][i] = P[b][i][p]  (transposed)
//   Aq[p][q] = A[p][q], later overwritten with Qt[q][i] = (P@A)[i][q]
__global__ __launch_bounds__(256) void gmat_kernel(
    const float* __restrict__ P, const int* __restrict__ d_hw,
    float* __restrict__ G)
{
    __shared__ float Pt[NLQ][PAD];
    __shared__ float Aq[NLQ][PAD];
    const int b = blockIdx.x;
    const int t = threadIdx.x;
    const float* Pb = P + b * NLQ * NLQ;
    for (int k = t; k < NLQ * NLQ; k += 256) {
        int row = k >> 7, col = k & 127;
        Pt[col][row] = Pb[k];                      // transpose into LDS
        Aq[row][col] = (d_hw[k] == 1) ? 1.f : 0.f;
    }
    __syncthreads();

    const int r0 = (t >> 4) * 8;   // 16x16 thread grid of 8x8 register tiles
    const int c0 = (t & 15) * 8;

    // Phase 1: Q[i][q] = sum_p P[i][p] * A[p][q]
    float acc[8][8];
    #pragma unroll
    for (int r = 0; r < 8; ++r)
        #pragma unroll
        for (int c = 0; c < 8; ++c) acc[r][c] = 0.f;
    for (int p = 0; p < NLQ; ++p) {
        float a[8], bv[8];
        #pragma unroll
        for (int r = 0; r < 8; ++r) a[r] = Pt[p][r0 + r];
        #pragma unroll
        for (int c = 0; c < 8; ++c) bv[c] = Aq[p][c0 + c];
        #pragma unroll
        for (int r = 0; r < 8; ++r)
            #pragma unroll
            for (int c = 0; c < 8; ++c) acc[r][c] += a[r] * bv[c];
    }
    __syncthreads();
    // Store transposed: Qt[q][i]
    #pragma unroll
    for (int r = 0; r < 8; ++r)
        #pragma unroll
        for (int c = 0; c < 8; ++c)
            Aq[c0 + c][r0 + r] = acc[r][c];
    __syncthreads();

    // Phase 2: G[i][j] += sum_q Qt[q][i] * Pt[q][j]
    #pragma unroll
    for (int r = 0; r < 8; ++r)
        #pragma unroll
        for (int c = 0; c < 8; ++c) acc[r][c] = 0.f;
    for (int q = 0; q < NLQ; ++q) {
        float a[8], bv[8];
        #pragma unroll
        for (int r = 0; r < 8; ++r) a[r] = Aq[q][r0 + r];
        #pragma unroll
        for (int c = 0; c < 8; ++c) bv[c] = Pt[q][c0 + c];
        #pragma unroll
        for (int r = 0; r < 8; ++r)
            #pragma unroll
            for (int c = 0; c < 8; ++c) acc[r][c] += a[r] * bv[c];
    }
    #pragma unroll
    for (int r = 0; r < 8; ++r)
        #pragma unroll
        for (int c = 0; c < 8; ++c)
            atomicAdd(&G[(r0 + r) * NLQ + c0 + c], acc[r][c]);
}

__global__ __launch_bounds__(256) void final_kernel(
    const float* __restrict__ M, const float* __restrict__ G,
    const float* __restrict__ totw, float* __restrict__ out)
{
    __shared__ float red[4];
    int t = threadIdx.x;
    float s = 0.f;
    for (int k = t; k < NLQ * NLQ; k += 256) s += M[k] * G[k];
    #pragma unroll
    for (int off = 32; off > 0; off >>= 1)
        s += __shfl_down(s, off, 64);
    if ((t & 63) == 0) red[t >> 6] = s;
    __syncthreads();
    if (t == 0) {
        float tot = red[0] + red[1] + red[2] + red[3];
        float tw = fmaxf(*totw, 1e-8f);
        out[0] = -(tot / (float)BATCH) / tw;
    }
}

extern "C" void kernel_launch(void* const* d_in, const int* in_sizes, int n_in,
                              void* d_out, int out_size, void* d_ws, size_t ws_size,
                              hipStream_t stream)
{
    const float* P     = (const float*)d_in[0];
    const int*   d_hw  = (const int*)d_in[1];
    const int*   pairs = (const int*)d_in[2];
    const float* w     = (const float*)d_in[3];
    const int    E     = in_sizes[3];

    float* M    = (float*)d_ws;
    float* G    = M + NLQ * NLQ;
    float* totw = G + NLQ * NLQ;

    // d_ws is poisoned (0xAA) and NOT re-zeroed between replays: zero it here.
    hipMemsetAsync(d_ws, 0, (2 * NLQ * NLQ + 1) * sizeof(float), stream);

    int eblocks = (E + 255) / 256;
    edges_kernel<<<dim3(eblocks), 256, 0, stream>>>(pairs, w, M, totw, E);
    gmat_kernel<<<dim3(BATCH), 256, 0, stream>>>(P, d_hw, G);
    final_kernel<<<dim3(1), 256, 0, stream>>>(M, G, totw, (float*)d_out);
}

// Round 2
// 38.597 us; speedup vs baseline: 2.0663x; 2.0663x over previous
//
#include <hip/hip_runtime.h>

// AdjacencyMatchingLoss: B=8, NL=NQ=128, E=50000
// loss = -(1/B)*sum_b <M^T P_b , P_b A^T> / max(sum_w,1e-8)
//   M[i,j] = scatter-add of edge weights, A = (d_hw==1)
// Identity: sum_{ij} M[ij] (P A P^T)[ij] = sum_{jq} (M^T P)[jq] * (P A^T)[jq]
// -> both matmuls are row(j)-tileable and the dot fuses elementwise: no
//    intermediate matrix, 64 independent blocks (8 batches x 8 j-tiles).

constexpr int N = 128;
constexpr int BATCH = 8;
constexpr int JT = 16;        // j-rows per block
constexpr int NJT = N / JT;   // 8 tiles
constexpr int APAD = 132;     // At row pad: keeps 16B-aligned b128 reads,
                              // spreads transposed staging writes over 8 banks
constexpr int MPAD = 20;      // Msl row pad (16B-aligned, fewer write conflicts)

__global__ __launch_bounds__(256) void edges_kernel(
    const int* __restrict__ pairs, const float* __restrict__ w,
    float* __restrict__ M, float* __restrict__ totw, int E)
{
    int idx = blockIdx.x * 256 + threadIdx.x;
    int stride = gridDim.x * 256;
    float wsum = 0.f;
    for (int e = idx; e < E; e += stride) {
        int2 ij = ((const int2*)pairs)[e];
        float we = w[e];
        atomicAdd(&M[ij.x * N + ij.y], we);
        wsum += we;
    }
    #pragma unroll
    for (int off = 32; off > 0; off >>= 1)
        wsum += __shfl_down(wsum, off, 64);
    if ((threadIdx.x & 63) == 0) atomicAdd(totw, wsum);
}

// One block per (batch b, j-tile). U = M^T P_b (rows j), W = P_b A^T (rows j),
// accumulate partial = sum U.*W over the tile, atomicAdd into tot.
__global__ __launch_bounds__(256) void uw_kernel(
    const float* __restrict__ P, const int* __restrict__ A,
    const float* __restrict__ M, float* __restrict__ tot)
{
    __shared__ float Pnat[N][N];     // 64 KB, natural: rows p/j, cols q/k
    __shared__ float At[N][APAD];    // 67.6 KB: At[p][q] = A[q][p] as float
    __shared__ float Msl[N][MPAD];   // 10 KB: Msl[i][j'] = M[i][j0g+j']

    const int t = threadIdx.x;
    const int b = blockIdx.x >> 3;
    const int j0g = (blockIdx.x & 7) * JT;
    const float* __restrict__ Pb = P + b * N * N;

    #pragma unroll
    for (int it = 0; it < 16; ++it) {             // stage P_b (coalesced)
        int idx = t + 256 * it;
        ((float4*)Pnat)[idx] = ((const float4*)Pb)[idx];
    }
    #pragma unroll
    for (int it = 0; it < 16; ++it) {             // stage A^T (transpose in LDS)
        int idx = t + 256 * it;
        int4 av = ((const int4*)A)[idx];
        int row = idx >> 5;          // A row q
        int col = (idx & 31) << 2;   // A col p
        At[col + 0][row] = (av.x == 1) ? 1.f : 0.f;
        At[col + 1][row] = (av.y == 1) ? 1.f : 0.f;
        At[col + 2][row] = (av.z == 1) ? 1.f : 0.f;
        At[col + 3][row] = (av.w == 1) ? 1.f : 0.f;
    }
    {                                             // stage M column-slice
        int i = t >> 1;
        int h = (t & 1) * 8;
        float4 m0 = *(const float4*)&M[i * N + j0g + h];
        float4 m1 = *(const float4*)&M[i * N + j0g + h + 4];
        *(float4*)&Msl[i][h]     = m0;
        *(float4*)&Msl[i][h + 4] = m1;
    }
    __syncthreads();

    const int q0 = (t & 31) << 2;   // 4 q-columns per thread
    const int jl = (t >> 5) << 1;   // 2 j-rows per thread (local)

    float u0[4] = {0,0,0,0}, u1[4] = {0,0,0,0};
    float w0[4] = {0,0,0,0}, w1[4] = {0,0,0,0};

    #pragma unroll 4
    for (int k = 0; k < N; ++k) {
        float4 bu = *(const float4*)&Pnat[k][q0];   // b128, shared rows
        float4 bw = *(const float4*)&At[k][q0];     // b128
        float a0 = Msl[k][jl];                      // 2-addr wave broadcast
        float a1 = Msl[k][jl + 1];
        float c0 = Pnat[j0g + jl][k];               // 2-addr wave broadcast
        float c1 = Pnat[j0g + jl + 1][k];
        u0[0] += a0 * bu.x; u0[1] += a0 * bu.y; u0[2] += a0 * bu.z; u0[3] += a0 * bu.w;
        u1[0] += a1 * bu.x; u1[1] += a1 * bu.y; u1[2] += a1 * bu.z; u1[3] += a1 * bu.w;
        w0[0] += c0 * bw.x; w0[1] += c0 * bw.y; w0[2] += c0 * bw.z; w0[3] += c0 * bw.w;
        w1[0] += c1 * bw.x; w1[1] += c1 * bw.y; w1[2] += c1 * bw.z; w1[3] += c1 * bw.w;
    }

    float s = u0[0]*w0[0] + u0[1]*w0[1] + u0[2]*w0[2] + u0[3]*w0[3]
            + u1[0]*w1[0] + u1[1]*w1[1] + u1[2]*w1[2] + u1[3]*w1[3];
    #pragma unroll
    for (int off = 32; off > 0; off >>= 1)
        s += __shfl_down(s, off, 64);
    if ((t & 63) == 0) atomicAdd(tot, s);
}

__global__ void final_kernel(const float* __restrict__ tot,
                             const float* __restrict__ totw,
                             float* __restrict__ out)
{
    float tw = fmaxf(*totw, 1e-8f);
    out[0] = -((*tot) / (float)BATCH) / tw;
}

extern "C" void kernel_launch(void* const* d_in, const int* in_sizes, int n_in,
                              void* d_out, int out_size, void* d_ws, size_t ws_size,
                              hipStream_t stream)
{
    const float* P     = (const float*)d_in[0];
    const int*   d_hw  = (const int*)d_in[1];
    const int*   pairs = (const int*)d_in[2];
    const float* w     = (const float*)d_in[3];
    const int    E     = in_sizes[3];

    float* M    = (float*)d_ws;
    float* tot  = M + N * N;
    float* totw = tot + 1;

    hipMemsetAsync(d_ws, 0, (N * N + 2) * sizeof(float), stream);
    edges_kernel<<<dim3(128), 256, 0, stream>>>(pairs, w, M, totw, E);
    uw_kernel<<<dim3(BATCH * NJT), 256, 0, stream>>>(P, d_hw, M, tot);
    final_kernel<<<dim3(1), 1, 0, stream>>>(tot, totw, (float*)d_out);
}